// Round 12
// baseline (350.637 us; speedup 1.0000x reference)
//
#include <hip/hip_runtime.h>
#include <hip/hip_bf16.h>

// B=2, S=128, H=12, DH=64, HID=768
// scores(b,h,i,j) = dot64(q+ra, k+rb)/8 + mask ; t = h*16384+i*128+j ; r=t/12, c=t%12
// ra = ip[r, 64c+d], rb = ip[r, 768+64c+d], ip = inference_path @ Wip (bf16 MFMA, never materialized)
// score block (b,r0) covers t in [12*r0, 12*r0+768) = 6 COMPLETE (h,i) rows -> softmax fused there.

typedef __attribute__((ext_vector_type(8))) __bf16 bf16x8;
typedef __attribute__((ext_vector_type(16))) float f32x16;
typedef __attribute__((ext_vector_type(4))) float f32x4;

// ws layout (total 7,208,960 B — proven footprint)
#define QKV_OFF   0u         // [256][2368] f32 : q|k|v|pv
#define ARENA_OFF 2424832u   // 2304 B-frags x 1KB bf16 (Wip), frag = n32*48 + k16
#define SC_OFF    4784128u   // [2][12][128][128] f32 (probs after fusion)
#define CTX_OFF   6356992u   // [256][832] f32

// ---------------- fused prep+proj (independent work, one launch) ----------------
__global__ __launch_bounds__(256)
void prep_proj_kernel(const float* __restrict__ Wip, __bf16* __restrict__ arena,
                      const float* __restrict__ hs,
                      const float* __restrict__ Wq, const float* __restrict__ bq,
                      const float* __restrict__ Wk, const float* __restrict__ bk,
                      const float* __restrict__ Wv, const float* __restrict__ bv,
                      const float* __restrict__ Wpv, const float* __restrict__ bpv,
                      float* __restrict__ qkv) {
  if (blockIdx.x < 576) {
    const int l = threadIdx.x & 63;
    const int f = blockIdx.x * 4 + (threadIdx.x >> 6);   // 0..2303
    const int n32 = f / 48, k16 = f - n32 * 48;
    const float* src = Wip + (size_t)(k16 * 16 + (l >> 5) * 8) * 1536 + n32 * 32 + (l & 31);
    union { __bf16 h[8]; uint4 u; } pk;
#pragma unroll
    for (int j = 0; j < 8; j++) pk.h[j] = (__bf16)src[(size_t)j * 1536];
    ((uint4*)arena)[(size_t)f * 64 + l] = pk.u;
    return;
  }
  const int pblk = blockIdx.x - 576;                     // 0..147
  const int n0 = (pblk % 74) * 32;                       // combined col space 2368
  const int m0 = (pblk / 74) * 128 + (threadIdx.x >> 6) * 32;
  const float* W; const float* bias; int noff, ldw;
  if (n0 < 768)       { W = Wq;  bias = bq;  noff = n0;        ldw = 768; }
  else if (n0 < 1536) { W = Wk;  bias = bk;  noff = n0 - 768;  ldw = 768; }
  else if (n0 < 2304) { W = Wv;  bias = bv;  noff = n0 - 1536; ldw = 768; }
  else                { W = Wpv; bias = bpv; noff = n0 - 2304; ldw = 64;  }
  const int l = threadIdx.x & 63;
  const int rsel = l & 31, ksel = l >> 5;
  f32x16 acc;
#pragma unroll
  for (int z = 0; z < 16; z++) acc[z] = 0.f;

#pragma unroll 4
  for (int k16 = 0; k16 < 48; k16++) {
    const float* ap = hs + (size_t)(m0 + rsel) * 768 + k16 * 16 + ksel * 8;
    float4 a0 = *(const float4*)ap;
    float4 a1 = *(const float4*)(ap + 4);
    union { __bf16 h[8]; bf16x8 v; } pa;
    pa.h[0] = (__bf16)a0.x; pa.h[1] = (__bf16)a0.y; pa.h[2] = (__bf16)a0.z; pa.h[3] = (__bf16)a0.w;
    pa.h[4] = (__bf16)a1.x; pa.h[5] = (__bf16)a1.y; pa.h[6] = (__bf16)a1.z; pa.h[7] = (__bf16)a1.w;
    const float* bp = W + (size_t)(k16 * 16 + ksel * 8) * ldw + noff + rsel;
    union { __bf16 h[8]; bf16x8 v; } pb;
#pragma unroll
    for (int j = 0; j < 8; j++) pb.h[j] = (__bf16)bp[(size_t)j * ldw];
    acc = __builtin_amdgcn_mfma_f32_32x32x16_bf16(pa.v, pb.v, acc, 0, 0, 0);
  }
#pragma unroll
  for (int reg = 0; reg < 16; reg++) {
    int row = (reg & 3) + ((reg >> 2) << 3) + (ksel << 2);
    qkv[(size_t)(m0 + row) * 2368 + n0 + rsel] = acc[reg] + bias[noff + rsel];
  }
}

// ---------------- score v8: 16-wave ra/rb split, regs FIT the 128 cap ----------------
// Geometry: 16 waves (1024 thr) = 4(wc) x 2(wd) x 2(wr: ra/rb). Per-wave live
// set = acc 32 + Af 32 + 2 B-banks 32 + addr ~25 = ~121 <= 128 (hard cap for
// 1024-thr blocks) -> banks/Af/acc simultaneously live at 4 waves/SIMD for the
// first time (R3 ran this split at a 64-cap; R1/R2 needed ~190). Padded A-LDS
// (R0), 2-bank B alternation, R3-proven LDS handoff epilogue, R9 softmax tail.
extern __shared__ char smem_raw[];

__global__ __launch_bounds__(1024, 2)
void score_kernel(const float* __restrict__ infp,
                  const __bf16* __restrict__ arena,
                  const float* __restrict__ qkv,
                  const float* __restrict__ mask,
                  float* __restrict__ probs) {
  char* Abase = smem_raw;                        // 96 frags * 1040 = 99840 B
  float* lds_sc = (float*)(smem_raw + 99840);    // 768 f32 = 3072 B
  float* hand   = (float*)(smem_raw + 102912);   // 32768 B ra->rb handoff
  const int tid = threadIdx.x;
  const int lane = tid & 63;
  const int ml = lane & 31;
  const int kh = lane >> 5;
  const int wv = tid >> 6;        // 0..15
  const int wv8 = wv & 7;
  const int wr = wv >> 3;         // 0 = ra-wave, 1 = rb-wave
  const int wc = wv8 & 3;
  const int wd = wv8 >> 2;
  const int blk = blockIdx.x;
  const int b = blk >> 8;
  const int r0 = (blk & 255) << 6;

  for (int z = tid; z < 768; z += 1024) lds_sc[z] = 0.f;

  // B stream: frag f = (2c+wd)*48 + kc*4 + ks ; wr selects ra / rb (+1152 frags)
  const uint4* bptr = (const uint4*)arena + (size_t)((2 * wc + wd) * 48) * 64
                      + (size_t)wr * 73728 + lane;
  int kpn = 0;
  bf16x8 B0[4], B1[4];
  bf16x8 Af[8];
  f32x16 acc[2];

  auto loadB = [&](bf16x8* dst) {
#pragma unroll
    for (int ks = 0; ks < 4; ks++) dst[ks] = *(const bf16x8*)(bptr + ks * 64);
    if (kpn == 11) { bptr += 21760; kpn = 0; } else { bptr += 256; kpn++; }
  };

  // prefetch slot-0 B: overlaps the HBM A-staging
  loadB(B0);

  // stage A: 64 rows x 768 f32 -> bf16 frag-ordered PADDED LDS (nt loads)
  {
    const f32x4* A4 = (const f32x4*)(infp + (size_t)(b * 16384 + r0) * 768);
#pragma unroll
    for (int p = 0; p < 6; p++) {
      int idx = p * 1024 + tid;                  // 0..6143
      int m = (int)(((unsigned)idx * 10923u) >> 20);   // idx/96
      int g = idx - m * 96;
      f32x4 v0 = __builtin_nontemporal_load(A4 + m * 192 + g * 2);
      f32x4 v1 = __builtin_nontemporal_load(A4 + m * 192 + g * 2 + 1);
      union { __bf16 h[8]; uint4 u; } pk;
      pk.h[0] = (__bf16)v0[0]; pk.h[1] = (__bf16)v0[1];
      pk.h[2] = (__bf16)v0[2]; pk.h[3] = (__bf16)v0[3];
      pk.h[4] = (__bf16)v1[0]; pk.h[5] = (__bf16)v1[1];
      pk.h[6] = (__bf16)v1[2]; pk.h[7] = (__bf16)v1[3];
      int F = (m >> 5) * 48 + (g >> 1);
      int slot = (m & 31) + ((g & 1) << 5);
      *(uint4*)(Abase + ((F * 65 + slot) << 4)) = pk.u;
    }
  }
  __syncthreads();

  const size_t lane_off = (size_t)(lane << 4);
  auto loadA = [&](int kcc) {
    const char* ab = Abase + lane_off + kcc * 4160;
#pragma unroll
    for (int mt = 0; mt < 2; mt++)
#pragma unroll
      for (int ks = 0; ks < 4; ks++)
        Af[mt * 4 + ks] = *(const bf16x8*)(ab + mt * 49920 + ks * 1040);
  };
  auto mfma_step = [&](const bf16x8* Bb) {
#pragma unroll
    for (int ks = 0; ks < 4; ks++)
#pragma unroll
      for (int mt = 0; mt < 2; mt++)
        acc[mt] = __builtin_amdgcn_mfma_f32_32x32x16_bf16(Af[mt * 4 + ks], Bb[ks], acc[mt], 0, 0, 0);
  };
  auto epilogue = [&](int c) {
    const int d = wd * 32 + ml;
#pragma unroll
    for (int mt = 0; mt < 2; mt++) {
      if (wr == 0) {
#pragma unroll
        for (int q = 0; q < 4; q++) {
          f32x4 w4;
          w4[0] = acc[mt][q * 4 + 0]; w4[1] = acc[mt][q * 4 + 1];
          w4[2] = acc[mt][q * 4 + 2]; w4[3] = acc[mt][q * 4 + 3];
          *(f32x4*)(hand + (wv8 * 4 + q) * 256 + lane * 4) = w4;
        }
      }
      __syncthreads();
      if (wr == 1) {
#pragma unroll
        for (int q = 0; q < 4; q++) {
          f32x4 ra4 = *(const f32x4*)(hand + (wv8 * 4 + q) * 256 + lane * 4);
          float qv[4], kv[4];
#pragma unroll
          for (int j = 0; j < 4; j++) {
            int row = mt * 32 + j + q * 8 + (kh << 2);
            int t = 12 * (r0 + row) + c;
            int hh = t >> 14;
            int ii = (t >> 7) & 127;
            int jj = t & 127;
            qv[j] = qkv[(size_t)((b << 7) + ii) * 2368 + (hh << 6) + d];
            kv[j] = qkv[(size_t)((b << 7) + jj) * 2368 + 768 + (hh << 6) + d];
          }
#pragma unroll
          for (int j = 0; j < 4; j++) {
            int row = mt * 32 + j + q * 8 + (kh << 2);
            float p = (qv[j] + ra4[j]) * (kv[j] + acc[mt][q * 4 + j]);
            p += __shfl_xor(p, 16);
            p += __shfl_xor(p, 8);
            p += __shfl_xor(p, 4);
            p += __shfl_xor(p, 2);
            p += __shfl_xor(p, 1);
            if (ml == 0) atomicAdd(&lds_sc[row * 12 + c], p);
          }
        }
      }
      __syncthreads();
    }
#pragma unroll
    for (int mt = 0; mt < 2; mt++)
#pragma unroll
      for (int z = 0; z < 16; z++) acc[mt][z] = 0.f;
  };

#pragma unroll
  for (int mt = 0; mt < 2; mt++)
#pragma unroll
    for (int z = 0; z < 16; z++) acc[mt][z] = 0.f;

  // 36 slots, 2-bank alternation: slot t prefetches slot t+1's B.
  int kc = 0, c = wc;
#pragma unroll 1
  for (int it = 0; it < 18; it++) {
    {
      loadB(B1);
      loadA(kc);
      mfma_step(B0);
      if (kc == 11) { epilogue(c); kc = 0; c += 4; } else kc++;
    }
    {
      if (it < 17) loadB(B0);
      loadA(kc);
      mfma_step(B1);
      if (kc == 11) { epilogue(c); kc = 0; c += 4; } else kc++;
    }
  }

  __syncthreads();
  // fused softmax tail: lds_sc flat z == t-offset (t = 12*r0 + z) -> 6 full rows.
  if (wv < 6) {
    const int z0 = wv << 7;
    float s0 = lds_sc[z0 + lane] * 0.125f + mask[b * 128 + lane];
    float s1 = lds_sc[z0 + lane + 64] * 0.125f + mask[b * 128 + lane + 64];
    float mx = fmaxf(s0, s1);
#pragma unroll
    for (int o = 32; o; o >>= 1) mx = fmaxf(mx, __shfl_xor(mx, o));
    float e0 = __expf(s0 - mx), e1 = __expf(s1 - mx);
    float sm = e0 + e1;
#pragma unroll
    for (int o = 32; o; o >>= 1) sm += __shfl_xor(sm, o);
    float inv = 1.f / sm;
    const int t0 = 12 * r0 + z0;
    const int hh = t0 >> 14;
    const int ii = (t0 >> 7) & 127;
    float* dst = probs + (size_t)((b * 12 + hh) * 128 + ii) * 128;
    dst[lane] = e0 * inv;
    dst[lane + 64] = e1 * inv;
  }
}

// ---------------- attn: pure PV (softmax fused into score) ----------------
__global__ __launch_bounds__(256)
void attn_kernel(const float* __restrict__ probs, const float* __restrict__ qkv,
                 const float* __restrict__ span, float* __restrict__ ctx) {
  const int i = blockIdx.x;
  const int b = blockIdx.y;
  const int tid = threadIdx.x;
  const int l = tid & 63;
  const int wvi = tid >> 6;
  __shared__ float w[13][132];
  for (int r = wvi; r < 13; r += 4) {
    const float* sp = (r < 12)
        ? probs + (size_t)((b * 12 + r) * 128 + i) * 128
        : span + (size_t)(b * 128 + i) * 128;
    w[r][l] = sp[l];
    w[r][l + 64] = sp[l + 64];
  }
  __syncthreads();
  if (tid < 208) {
    const int h = tid >> 4;
    const int d4 = (tid & 15) << 2;
    const float* vp = qkv + (size_t)(b * 128) * 2368 + (h < 12 ? 1536 + h * 64 : 2304) + d4;
    f32x4 acc = {0.f, 0.f, 0.f, 0.f};
#pragma unroll 8
    for (int j = 0; j < 128; j++) {
      f32x4 v = *(const f32x4*)(vp + (size_t)j * 2368);
      float ww = w[h][j];
      acc[0] += ww * v[0]; acc[1] += ww * v[1];
      acc[2] += ww * v[2]; acc[3] += ww * v[3];
    }
    *(f32x4*)(ctx + (size_t)(b * 128 + i) * 832 + (h < 12 ? h * 64 : 768) + d4) = acc;
  }
}

// ---------------- out v2: (24 n-tiles, 2 m-supers) x 256 thr (4 waves = 4 m-tiles) ----------------
__global__ __launch_bounds__(256)
void out_kernel(const float* __restrict__ ctxb, const float* __restrict__ Wmlp,
                const float* __restrict__ bmlp, float* __restrict__ out) {
  const int n0 = blockIdx.x * 32;
  const int m0 = blockIdx.y * 128 + (threadIdx.x >> 6) * 32;
  const int l = threadIdx.x & 63;
  const int rsel = l & 31, ksel = l >> 5;
  f32x16 acc;
#pragma unroll
  for (int z = 0; z < 16; z++) acc[z] = 0.f;

#pragma unroll 4
  for (int k16 = 0; k16 < 52; k16++) {
    const float* ap = ctxb + (size_t)(m0 + rsel) * 832 + k16 * 16 + ksel * 8;
    float4 a0 = *(const float4*)ap;
    float4 a1 = *(const float4*)(ap + 4);
    union { __bf16 h[8]; bf16x8 v; } pa;
    pa.h[0] = (__bf16)a0.x; pa.h[1] = (__bf16)a0.y; pa.h[2] = (__bf16)a0.z; pa.h[3] = (__bf16)a0.w;
    pa.h[4] = (__bf16)a1.x; pa.h[5] = (__bf16)a1.y; pa.h[6] = (__bf16)a1.z; pa.h[7] = (__bf16)a1.w;
    const float* bp = Wmlp + (size_t)(k16 * 16 + ksel * 8) * 768 + n0 + rsel;
    union { __bf16 h[8]; bf16x8 v; } pb;
#pragma unroll
    for (int j = 0; j < 8; j++) pb.h[j] = (__bf16)bp[(size_t)j * 768];
    acc = __builtin_amdgcn_mfma_f32_32x32x16_bf16(pa.v, pb.v, acc, 0, 0, 0);
  }
#pragma unroll
  for (int reg = 0; reg < 16; reg++) {
    int row = (reg & 3) + ((reg >> 2) << 3) + (ksel << 2);
    out[(size_t)(m0 + row) * 768 + n0 + rsel] = acc[reg] + bmlp[n0 + rsel];
  }
}

// ---------------- launch ----------------
extern "C" void kernel_launch(void* const* d_in, const int* in_sizes, int n_in,
                              void* d_out, int out_size, void* d_ws, size_t ws_size,
                              hipStream_t stream) {
  const float* hs   = (const float*)d_in[0];
  const float* mask = (const float*)d_in[1];
  const float* infp = (const float*)d_in[2];
  const float* span = (const float*)d_in[3];
  const float* Wq   = (const float*)d_in[4];
  const float* bq   = (const float*)d_in[5];
  const float* Wk   = (const float*)d_in[6];
  const float* bk   = (const float*)d_in[7];
  const float* Wv   = (const float*)d_in[8];
  const float* bv   = (const float*)d_in[9];
  const float* Wpv  = (const float*)d_in[10];
  const float* bpv  = (const float*)d_in[11];
  const float* Wip  = (const float*)d_in[12];
  const float* Wmlp = (const float*)d_in[13];
  const float* bmlp = (const float*)d_in[14];
  float* out = (float*)d_out;

  char* ws = (char*)d_ws;
  float*  qkv    = (float*)(ws + QKV_OFF);
  __bf16* arena  = (__bf16*)(ws + ARENA_OFF);
  float*  probs  = (float*)(ws + SC_OFF);
  float*  ctx    = (float*)(ws + CTX_OFF);

  prep_proj_kernel<<<dim3(724), 256, 0, stream>>>(Wip, arena, hs,
      Wq, bq, Wk, bk, Wv, bv, Wpv, bpv, qkv);
  score_kernel<<<dim3(512), 1024, 135680, stream>>>(infp, arena, qkv, mask, probs);
  attn_kernel<<<dim3(128, 2), 256, 0, stream>>>(probs, qkv, span, ctx);
  out_kernel<<<dim3(24, 2), 256, 0, stream>>>(ctx, Wmlp, bmlp, out);
}

// Round 13
// 329.650 us; speedup vs baseline: 1.0637x; 1.0637x over previous
//
#include <hip/hip_runtime.h>
#include <hip/hip_bf16.h>

// B=2, S=128, H=12, DH=64, HID=768
// scores(b,h,i,j) = dot64(q+ra, k+rb)/8 + mask ; t = h*16384+i*128+j ; r=t/12, c=t%12
// ra = ip[r, 64c+d], rb = ip[r, 768+64c+d], ip = inference_path @ Wip (bf16 MFMA, never materialized)
// score block (b,r0) covers t in [12*r0, 12*r0+768) = 6 COMPLETE (h,i) rows -> softmax fused there.
// FINAL: R9-exact configuration (measured best: 321.5 us R9, 330.2 us R11).

typedef __attribute__((ext_vector_type(8))) __bf16 bf16x8;
typedef __attribute__((ext_vector_type(16))) float f32x16;
typedef __attribute__((ext_vector_type(4))) float f32x4;

// ws layout (total 7,208,960 B — proven footprint)
#define QKV_OFF   0u         // [256][2368] f32 : q|k|v|pv
#define ARENA_OFF 2424832u   // 2304 B-frags x 1KB bf16 (Wip), frag = n32*48 + k16
#define SC_OFF    4784128u   // [2][12][128][128] f32 (probs after fusion)
#define CTX_OFF   6356992u   // [256][832] f32

// ---------------- fused prep+proj (independent work, one launch) ----------------
// blocks 0..575: prep — Wip [768][1536] f32 -> bf16 B-frags
// blocks 576..723: proj — 4 waves = 4 m-tiles of the wave-block MFMA GEMM
__global__ __launch_bounds__(256)
void prep_proj_kernel(const float* __restrict__ Wip, __bf16* __restrict__ arena,
                      const float* __restrict__ hs,
                      const float* __restrict__ Wq, const float* __restrict__ bq,
                      const float* __restrict__ Wk, const float* __restrict__ bk,
                      const float* __restrict__ Wv, const float* __restrict__ bv,
                      const float* __restrict__ Wpv, const float* __restrict__ bpv,
                      float* __restrict__ qkv) {
  if (blockIdx.x < 576) {
    // ---- prep: frag f = n32*48 + k16 ; lane l: col = n32*32+(l&31), k = k16*16+(l>>5)*8+j
    const int l = threadIdx.x & 63;
    const int f = blockIdx.x * 4 + (threadIdx.x >> 6);   // 0..2303
    const int n32 = f / 48, k16 = f - n32 * 48;
    const float* src = Wip + (size_t)(k16 * 16 + (l >> 5) * 8) * 1536 + n32 * 32 + (l & 31);
    union { __bf16 h[8]; uint4 u; } pk;
#pragma unroll
    for (int j = 0; j < 8; j++) pk.h[j] = (__bf16)src[(size_t)j * 1536];
    ((uint4*)arena)[(size_t)f * 64 + l] = pk.u;
    return;
  }
  // ---- proj: pblk -> (n-tile, m-quad); wave = m-tile within quad
  const int pblk = blockIdx.x - 576;                     // 0..147
  const int n0 = (pblk % 74) * 32;                       // combined col space 2368
  const int m0 = (pblk / 74) * 128 + (threadIdx.x >> 6) * 32;
  const float* W; const float* bias; int noff, ldw;
  if (n0 < 768)       { W = Wq;  bias = bq;  noff = n0;        ldw = 768; }
  else if (n0 < 1536) { W = Wk;  bias = bk;  noff = n0 - 768;  ldw = 768; }
  else if (n0 < 2304) { W = Wv;  bias = bv;  noff = n0 - 1536; ldw = 768; }
  else                { W = Wpv; bias = bpv; noff = n0 - 2304; ldw = 64;  }
  const int l = threadIdx.x & 63;
  const int rsel = l & 31, ksel = l >> 5;
  f32x16 acc;
#pragma unroll
  for (int z = 0; z < 16; z++) acc[z] = 0.f;

#pragma unroll 4
  for (int k16 = 0; k16 < 48; k16++) {
    const float* ap = hs + (size_t)(m0 + rsel) * 768 + k16 * 16 + ksel * 8;
    float4 a0 = *(const float4*)ap;
    float4 a1 = *(const float4*)(ap + 4);
    union { __bf16 h[8]; bf16x8 v; } pa;
    pa.h[0] = (__bf16)a0.x; pa.h[1] = (__bf16)a0.y; pa.h[2] = (__bf16)a0.z; pa.h[3] = (__bf16)a0.w;
    pa.h[4] = (__bf16)a1.x; pa.h[5] = (__bf16)a1.y; pa.h[6] = (__bf16)a1.z; pa.h[7] = (__bf16)a1.w;
    const float* bp = W + (size_t)(k16 * 16 + ksel * 8) * ldw + noff + rsel;
    union { __bf16 h[8]; bf16x8 v; } pb;
#pragma unroll
    for (int j = 0; j < 8; j++) pb.h[j] = (__bf16)bp[(size_t)j * ldw];
    acc = __builtin_amdgcn_mfma_f32_32x32x16_bf16(pa.v, pb.v, acc, 0, 0, 0);
  }
#pragma unroll
  for (int reg = 0; reg < 16; reg++) {
    int row = (reg & 3) + ((reg >> 2) << 3) + (ksel << 2);
    qkv[(size_t)(m0 + row) * 2368 + n0 + rsel] = acc[reg] + bias[noff + rsel];
  }
}

// ---------------- score: fused ip-GEMM + score reduction + SOFTMAX ----------------
// Core FROZEN (R2-proven). Tail: the block's lds_sc[768] is 6 complete
// (h,i) rows -> apply *0.125 + mask + softmax here, write PROBS. (R9-exact.)
extern __shared__ char smem_raw[];

__global__ __launch_bounds__(512, 2)
void score_kernel(const float* __restrict__ infp,
                  const __bf16* __restrict__ arena,
                  const float* __restrict__ qkv,
                  const float* __restrict__ mask,
                  float* __restrict__ probs) {
  char* Abase = smem_raw;                        // 96 frags * 1040 = 99840 B
  float* lds_sc = (float*)(smem_raw + 99840);    // 64*12 floats
  const int tid = threadIdx.x;
  const int lane = tid & 63;
  const int ml = lane & 31;
  const int kh = lane >> 5;
  const int wv = tid >> 6;
  const int wc = wv & 3;
  const int wd = wv >> 2;
  const int blk = blockIdx.x;
  const int b = blk >> 8;
  const int r0 = (blk & 255) << 6;

  for (int z = tid; z < 768; z += 512) lds_sc[z] = 0.f;

  const uint4* BA = (const uint4*)arena;
  const uint4* bptr  = BA + (size_t)((2 * wc + wd) * 48) * 64 + lane;
  const uint4* bptr2 = bptr + 73728;
  int kpn = 0;                                   // kc the pointer targets
  uint4 B0[8], B1[8], B2[8];
  bf16x8 Af[8];
  f32x16 acc_ra[2], acc_rb[2];

  auto loadB = [&](uint4* dst) {
#pragma unroll
    for (int ks = 0; ks < 4; ks++) {
      dst[ks * 2]     = bptr[ks * 64];           // ra (cols < 768)
      dst[ks * 2 + 1] = bptr2[ks * 64];          // rb (+1152 frags)
    }
    if (kpn == 11) { bptr += 21760; bptr2 += 21760; kpn = 0; }
    else           { bptr += 256;   bptr2 += 256;   kpn++;  }
  };

  // prefetch B for slots 0 and 1: overlaps the HBM A-staging below
  loadB(B0);
  loadB(B1);

  // stage A: 64 rows x 768 f32 -> bf16 frag-ordered LDS (HBM read-once, nt)
  {
    const f32x4* A4 = (const f32x4*)(infp + (size_t)(b * 16384 + r0) * 768);
#pragma unroll
    for (int p = 0; p < 12; p++) {
      int idx = p * 512 + tid;
      int m = (int)(((unsigned)idx * 10923u) >> 20);   // idx/96
      int g = idx - m * 96;
      f32x4 v0 = __builtin_nontemporal_load(A4 + m * 192 + g * 2);
      f32x4 v1 = __builtin_nontemporal_load(A4 + m * 192 + g * 2 + 1);
      union { __bf16 h[8]; uint4 u; } pk;
      pk.h[0] = (__bf16)v0[0]; pk.h[1] = (__bf16)v0[1];
      pk.h[2] = (__bf16)v0[2]; pk.h[3] = (__bf16)v0[3];
      pk.h[4] = (__bf16)v1[0]; pk.h[5] = (__bf16)v1[1];
      pk.h[6] = (__bf16)v1[2]; pk.h[7] = (__bf16)v1[3];
      int F = (m >> 5) * 48 + (g >> 1);
      int slot = (m & 31) + ((g & 1) << 5);
      *(uint4*)(Abase + ((F * 65 + slot) << 4)) = pk.u;
    }
  }
  __syncthreads();

  const size_t lane_off = (size_t)(lane << 4);
  auto loadA = [&](int kcc) {
    const char* ab = Abase + lane_off + kcc * 4160;
#pragma unroll
    for (int mt = 0; mt < 2; mt++)
#pragma unroll
      for (int ks = 0; ks < 4; ks++)
        Af[mt * 4 + ks] = *(const bf16x8*)(ab + mt * 49920 + ks * 1040);
  };
  auto mfma_step = [&](const uint4* Bb) {
#pragma unroll
    for (int ks = 0; ks < 4; ks++) {
      bf16x8 bra = __builtin_bit_cast(bf16x8, Bb[ks * 2]);
      bf16x8 brb = __builtin_bit_cast(bf16x8, Bb[ks * 2 + 1]);
#pragma unroll
      for (int mt = 0; mt < 2; mt++) {
        acc_ra[mt] = __builtin_amdgcn_mfma_f32_32x32x16_bf16(Af[mt * 4 + ks], bra, acc_ra[mt], 0, 0, 0);
        acc_rb[mt] = __builtin_amdgcn_mfma_f32_32x32x16_bf16(Af[mt * 4 + ks], brb, acc_rb[mt], 0, 0, 0);
      }
    }
  };
  auto epilogue = [&](int c) {
    int d = wd * 32 + ml;
#pragma unroll
    for (int mt = 0; mt < 2; mt++) {
      float qv[16], kv[16];
#pragma unroll
      for (int reg = 0; reg < 16; reg++) {
        int row = mt * 32 + (reg & 3) + ((reg >> 2) << 3) + (kh << 2);
        int t = 12 * (r0 + row) + c;
        int hh = t >> 14;
        int ii = (t >> 7) & 127;
        int jj = t & 127;
        qv[reg] = qkv[(size_t)((b << 7) + ii) * 2368 + (hh << 6) + d];
        kv[reg] = qkv[(size_t)((b << 7) + jj) * 2368 + 768 + (hh << 6) + d];
      }
#pragma unroll
      for (int reg = 0; reg < 16; reg++) {
        int row = mt * 32 + (reg & 3) + ((reg >> 2) << 3) + (kh << 2);
        float p = (qv[reg] + acc_ra[mt][reg]) * (kv[reg] + acc_rb[mt][reg]);
        p += __shfl_xor(p, 16);
        p += __shfl_xor(p, 8);
        p += __shfl_xor(p, 4);
        p += __shfl_xor(p, 2);
        p += __shfl_xor(p, 1);
        if (ml == 0) atomicAdd(&lds_sc[row * 12 + c], p);
      }
    }
#pragma unroll
    for (int mt = 0; mt < 2; mt++)
#pragma unroll
      for (int z = 0; z < 16; z++) { acc_ra[mt][z] = 0.f; acc_rb[mt][z] = 0.f; }
  };

#pragma unroll
  for (int mt = 0; mt < 2; mt++)
#pragma unroll
    for (int z = 0; z < 16; z++) { acc_ra[mt][z] = 0.f; acc_rb[mt][z] = 0.f; }

  // 36 slots = 12 iters x 3, banks rotate statically: consume B0,B1,B2 ;
  // slot t prefetches slot t+2's frags into the bank freed at t-1.
  int kcc = 0, cc = wc;
#pragma unroll 1
  for (int it = 0; it < 12; it++) {
    {  // slot 3it+0 : consume B0, prefetch slot 3it+2 -> B2
      loadB(B2);
      loadA(kcc);
      mfma_step(B0);
      if (kcc == 11) { epilogue(cc); kcc = 0; cc += 4; } else kcc++;
    }
    {  // slot 3it+1 : consume B1, prefetch slot 3it+3 -> B0
      if (it < 11) loadB(B0);
      loadA(kcc);
      mfma_step(B1);
      if (kcc == 11) { epilogue(cc); kcc = 0; cc += 4; } else kcc++;
    }
    {  // slot 3it+2 : consume B2, prefetch slot 3it+4 -> B1
      if (it < 11) loadB(B1);
      loadA(kcc);
      mfma_step(B2);
      if (kcc == 11) { epilogue(cc); kcc = 0; cc += 4; } else kcc++;
    }
  }

  __syncthreads();
  // fused softmax tail: lds_sc flat z == t-offset (t = 12*r0 + z) -> 6 full rows.
  // wave rr (0..5) handles row rr: lanes hold j = lane and j = lane+64.
  if (wv < 6) {
    const int z0 = wv << 7;
    float s0 = lds_sc[z0 + lane] * 0.125f + mask[b * 128 + lane];
    float s1 = lds_sc[z0 + lane + 64] * 0.125f + mask[b * 128 + lane + 64];
    float mx = fmaxf(s0, s1);
#pragma unroll
    for (int o = 32; o; o >>= 1) mx = fmaxf(mx, __shfl_xor(mx, o));
    float e0 = __expf(s0 - mx), e1 = __expf(s1 - mx);
    float sm = e0 + e1;
#pragma unroll
    for (int o = 32; o; o >>= 1) sm += __shfl_xor(sm, o);
    float inv = 1.f / sm;
    const int t0 = 12 * r0 + z0;
    const int hh = t0 >> 14;
    const int ii = (t0 >> 7) & 127;
    float* dst = probs + (size_t)((b * 12 + hh) * 128 + ii) * 128;
    dst[lane] = e0 * inv;
    dst[lane + 64] = e1 * inv;
  }
}

// ---------------- attn: pure PV (softmax fused into score) ----------------
// one (b,i) per block; stage 13 weight rows (probs / span) into LDS, then
// float4-vectorized PV: 208 threads, h = tid>>4, d4 = (tid&15)*4.
__global__ __launch_bounds__(256)
void attn_kernel(const float* __restrict__ probs, const float* __restrict__ qkv,
                 const float* __restrict__ span, float* __restrict__ ctx) {
  const int i = blockIdx.x;
  const int b = blockIdx.y;
  const int tid = threadIdx.x;
  const int l = tid & 63;
  const int wvi = tid >> 6;
  __shared__ float w[13][132];
  for (int r = wvi; r < 13; r += 4) {
    const float* sp = (r < 12)
        ? probs + (size_t)((b * 12 + r) * 128 + i) * 128
        : span + (size_t)(b * 128 + i) * 128;
    w[r][l] = sp[l];
    w[r][l + 64] = sp[l + 64];
  }
  __syncthreads();
  if (tid < 208) {
    const int h = tid >> 4;
    const int d4 = (tid & 15) << 2;
    const float* vp = qkv + (size_t)(b * 128) * 2368 + (h < 12 ? 1536 + h * 64 : 2304) + d4;
    f32x4 acc = {0.f, 0.f, 0.f, 0.f};
#pragma unroll 8
    for (int j = 0; j < 128; j++) {
      f32x4 v = *(const f32x4*)(vp + (size_t)j * 2368);
      float ww = w[h][j];
      acc[0] += ww * v[0]; acc[1] += ww * v[1];
      acc[2] += ww * v[2]; acc[3] += ww * v[3];
    }
    *(f32x4*)(ctx + (size_t)(b * 128 + i) * 832 + (h < 12 ? h * 64 : 768) + d4) = acc;
  }
}

// ---------------- out v2: (24 n-tiles, 2 m-supers) x 256 thr (4 waves = 4 m-tiles) ----------------
// 4 waves share the Wmlp fragment stream (L1 hits).
__global__ __launch_bounds__(256)
void out_kernel(const float* __restrict__ ctxb, const float* __restrict__ Wmlp,
                const float* __restrict__ bmlp, float* __restrict__ out) {
  const int n0 = blockIdx.x * 32;
  const int m0 = blockIdx.y * 128 + (threadIdx.x >> 6) * 32;
  const int l = threadIdx.x & 63;
  const int rsel = l & 31, ksel = l >> 5;
  f32x16 acc;
#pragma unroll
  for (int z = 0; z < 16; z++) acc[z] = 0.f;

#pragma unroll 4
  for (int k16 = 0; k16 < 52; k16++) {
    const float* ap = ctxb + (size_t)(m0 + rsel) * 832 + k16 * 16 + ksel * 8;
    float4 a0 = *(const float4*)ap;
    float4 a1 = *(const float4*)(ap + 4);
    union { __bf16 h[8]; bf16x8 v; } pa;
    pa.h[0] = (__bf16)a0.x; pa.h[1] = (__bf16)a0.y; pa.h[2] = (__bf16)a0.z; pa.h[3] = (__bf16)a0.w;
    pa.h[4] = (__bf16)a1.x; pa.h[5] = (__bf16)a1.y; pa.h[6] = (__bf16)a1.z; pa.h[7] = (__bf16)a1.w;
    const float* bp = Wmlp + (size_t)(k16 * 16 + ksel * 8) * 768 + n0 + rsel;
    union { __bf16 h[8]; bf16x8 v; } pb;
#pragma unroll
    for (int j = 0; j < 8; j++) pb.h[j] = (__bf16)bp[(size_t)j * 768];
    acc = __builtin_amdgcn_mfma_f32_32x32x16_bf16(pa.v, pb.v, acc, 0, 0, 0);
  }
#pragma unroll
  for (int reg = 0; reg < 16; reg++) {
    int row = (reg & 3) + ((reg >> 2) << 3) + (ksel << 2);
    out[(size_t)(m0 + row) * 768 + n0 + rsel] = acc[reg] + bmlp[n0 + rsel];
  }
}

// ---------------- launch ----------------
extern "C" void kernel_launch(void* const* d_in, const int* in_sizes, int n_in,
                              void* d_out, int out_size, void* d_ws, size_t ws_size,
                              hipStream_t stream) {
  const float* hs   = (const float*)d_in[0];
  const float* mask = (const float*)d_in[1];
  const float* infp = (const float*)d_in[2];
  const float* span = (const float*)d_in[3];
  const float* Wq   = (const float*)d_in[4];
  const float* bq   = (const float*)d_in[5];
  const float* Wk   = (const float*)d_in[6];
  const float* bk   = (const float*)d_in[7];
  const float* Wv   = (const float*)d_in[8];
  const float* bv   = (const float*)d_in[9];
  const float* Wpv  = (const float*)d_in[10];
  const float* bpv  = (const float*)d_in[11];
  const float* Wip  = (const float*)d_in[12];
  const float* Wmlp = (const float*)d_in[13];
  const float* bmlp = (const float*)d_in[14];
  float* out = (float*)d_out;

  char* ws = (char*)d_ws;
  float*  qkv    = (float*)(ws + QKV_OFF);
  __bf16* arena  = (__bf16*)(ws + ARENA_OFF);
  float*  probs  = (float*)(ws + SC_OFF);
  float*  ctx    = (float*)(ws + CTX_OFF);

  prep_proj_kernel<<<dim3(724), 256, 0, stream>>>(Wip, arena, hs,
      Wq, bq, Wk, bk, Wv, bv, Wpv, bpv, qkv);
  score_kernel<<<dim3(512), 512, 102912, stream>>>(infp, arena, qkv, mask, probs);
  attn_kernel<<<dim3(128, 2), 256, 0, stream>>>(probs, qkv, span, ctx);
  out_kernel<<<dim3(24, 2), 256, 0, stream>>>(ctx, Wmlp, bmlp, out);
}